// Round 1
// baseline (138.486 us; speedup 1.0000x reference)
//
#include <hip/hip_runtime.h>
#include <math.h>

#define N_RAYS 262144
#define N_SPHERES 256

__global__ __launch_bounds__(256) void ray_sphere_kernel(
    const float* __restrict__ ro,   // (N,3)
    const float* __restrict__ rd,   // (N,3)
    const float* __restrict__ sc,   // (M,3)
    const float* __restrict__ sr,   // (M,)
    float* __restrict__ out)        // 8N floats: t_hit | idx | hit_points | hit_normals
{
    __shared__ float4 sph[N_SPHERES];  // x,y,z = center, w = |c|^2 - r^2

    const int tid = threadIdx.x;
    // Stage sphere data (blockDim == N_SPHERES == 256)
    {
        float cx = sc[3 * tid + 0];
        float cy = sc[3 * tid + 1];
        float cz = sc[3 * tid + 2];
        float r  = sr[tid];
        sph[tid] = make_float4(cx, cy, cz, cx * cx + cy * cy + cz * cz - r * r);
    }
    __syncthreads();

    const int i = blockIdx.x * blockDim.x + tid;

    const float ox = ro[3 * i + 0], oy = ro[3 * i + 1], oz = ro[3 * i + 2];
    const float dx = rd[3 * i + 0], dy = rd[3 * i + 1], dz = rd[3 * i + 2];

    const float a       = dx * dx + dy * dy + dz * dz;
    const float d_dot_o = dx * ox + dy * oy + dz * oz;
    const float o_norm2 = ox * ox + oy * oy + oz * oz;
    const float inv2a   = 1.0f / (2.0f * a);

    float best_t = INFINITY;
    int   best_j = 0;  // argmin of all-inf row is 0 (matches jnp.argmin)

    #pragma unroll 4
    for (int j = 0; j < N_SPHERES; ++j) {
        const float4 s = sph[j];
        const float d_dot_c = dx * s.x + dy * s.y + dz * s.z;
        const float o_dot_c = ox * s.x + oy * s.y + oz * s.z;
        const float b = 2.0f * (d_dot_o - d_dot_c);
        const float c = o_norm2 - 2.0f * o_dot_c + s.w;
        const float disc = b * b - 4.0f * a * c;
        const float sq = sqrtf(fmaxf(disc, 0.0f));
        const float t1 = (-b - sq) * inv2a;
        const float t2 = (-b + sq) * inv2a;
        const float t  = (t1 > 0.0f) ? t1 : t2;
        const bool valid = (disc >= 0.0f) && (t > 0.0f);
        const float tm = valid ? t : INFINITY;
        // strict < keeps the FIRST minimum -> matches jnp.argmin tie-break
        if (tm < best_t) { best_t = tm; best_j = j; }
    }

    const bool any_hit = isfinite(best_t);

    // hit point (setup guarantees a hit, so best_t finite in practice)
    const float hx = ox + best_t * dx;
    const float hy = oy + best_t * dy;
    const float hz = oz + best_t * dz;

    // normal: (hp - center[jmin_safe]) normalized; zeros for miss
    const float4 cs = sph[any_hit ? best_j : 0];
    float nx = hx - cs.x, ny = hy - cs.y, nz = hz - cs.z;
    const float nrm = sqrtf(nx * nx + ny * ny + nz * nz);
    const float inv_nrm = 1.0f / nrm;
    nx *= inv_nrm; ny *= inv_nrm; nz *= inv_nrm;
    if (!any_hit) { nx = 0.0f; ny = 0.0f; nz = 0.0f; }

    // outputs: t_hit [0,N) | sphere_idx [N,2N) | hit_points [2N,5N) | normals [5N,8N)
    out[i]            = best_t;
    out[N_RAYS + i]   = any_hit ? (float)best_j : -1.0f;
    float* hp = out + 2 * N_RAYS;
    hp[3 * i + 0] = hx; hp[3 * i + 1] = hy; hp[3 * i + 2] = hz;
    float* hn = out + 5 * N_RAYS;
    hn[3 * i + 0] = nx; hn[3 * i + 1] = ny; hn[3 * i + 2] = nz;
}

extern "C" void kernel_launch(void* const* d_in, const int* in_sizes, int n_in,
                              void* d_out, int out_size, void* d_ws, size_t ws_size,
                              hipStream_t stream) {
    const float* ro = (const float*)d_in[0];
    const float* rd = (const float*)d_in[1];
    const float* sc = (const float*)d_in[2];
    const float* sr = (const float*)d_in[3];
    float* out = (float*)d_out;

    dim3 block(256);
    dim3 grid(N_RAYS / 256);
    ray_sphere_kernel<<<grid, block, 0, stream>>>(ro, rd, sc, sr, out);
}

// Round 2
// 100.560 us; speedup vs baseline: 1.3772x; 1.3772x over previous
//
#include <hip/hip_runtime.h>
#include <math.h>

#define N_RAYS 262144
#define N_SPHERES 256

__global__ __launch_bounds__(256) void ray_sphere_kernel(
    const float* __restrict__ ro,   // (N,3)
    const float* __restrict__ rd,   // (N,3)
    const float* __restrict__ sc,   // (M,3)
    const float* __restrict__ sr,   // (M,)
    float* __restrict__ out)        // 8N floats: t_hit | idx | hit_points | hit_normals
{
    __shared__ float4 sph[N_SPHERES];  // x,y,z = center, w = |c|^2 - r^2

    const int tid = threadIdx.x;
    // Stage sphere data (blockDim == N_SPHERES == 256)
    {
        const float cx = sc[3 * tid + 0];
        const float cy = sc[3 * tid + 1];
        const float cz = sc[3 * tid + 2];
        const float r  = sr[tid];
        sph[tid] = make_float4(cx, cy, cz,
                               fmaf(cz, cz, fmaf(cy, cy, cx * cx)) - r * r);
    }
    __syncthreads();

    const int i = blockIdx.x * blockDim.x + tid;

    const float ox = ro[3 * i + 0], oy = ro[3 * i + 1], oz = ro[3 * i + 2];
    const float dx = rd[3 * i + 0], dy = rd[3 * i + 1], dz = rd[3 * i + 2];

    const float a       = fmaf(dz, dz, fmaf(dy, dy, dx * dx));
    const float d_dot_o = fmaf(dz, oz, fmaf(dy, oy, dx * ox));
    const float o_norm2 = fmaf(oz, oz, fmaf(oy, oy, ox * ox));
    const float inva    = 1.0f / a;       // once per ray, full-precision divide

    float best_t = INFINITY;
    int   best_j = 0;  // argmin of all-inf row is 0 (matches jnp.argmin)

    // Half-b quadratic: hb = b/2, disc4 = disc/4; t = (-hb -+ sqrt(disc4))/a.
    // sqrt(disc) == 2*sqrt(disc4) (exact scaling), so root selection matches
    // the reference to ~1 ulp.
    #pragma unroll 8
    for (int j = 0; j < N_SPHERES; ++j) {
        const float4 s = sph[j];
        const float d_dot_c = fmaf(dz, s.z, fmaf(dy, s.y, dx * s.x));
        const float o_dot_c = fmaf(oz, s.z, fmaf(oy, s.y, ox * s.x));
        const float hb   = d_dot_o - d_dot_c;                    // b/2
        const float c    = fmaf(-2.0f, o_dot_c, o_norm2 + s.w);
        const float disc = fmaf(hb, hb, -(a * c));               // disc/4
        const float sq   = __builtin_amdgcn_sqrtf(fmaxf(disc, 0.0f)); // v_sqrt_f32
        const float t1   = (-hb - sq) * inva;
        const float t2   = (sq - hb) * inva;
        const float t    = (t1 > 0.0f) ? t1 : t2;
        const bool valid = (disc >= 0.0f) && (t > 0.0f);
        const float tm   = valid ? t : INFINITY;
        // strict < keeps the FIRST minimum -> matches jnp.argmin tie-break
        if (tm < best_t) { best_t = tm; best_j = j; }
    }

    const bool any_hit = isfinite(best_t);

    // hit point
    const float hx = fmaf(best_t, dx, ox);
    const float hy = fmaf(best_t, dy, oy);
    const float hz = fmaf(best_t, dz, oz);

    // normal: (hp - center[jmin_safe]) normalized; zeros for miss
    const float4 cs = sph[any_hit ? best_j : 0];
    float nx = hx - cs.x, ny = hy - cs.y, nz = hz - cs.z;
    const float inv_nrm = __builtin_amdgcn_rsqf(fmaf(nz, nz, fmaf(ny, ny, nx * nx)));
    nx *= inv_nrm; ny *= inv_nrm; nz *= inv_nrm;
    if (!any_hit) { nx = 0.0f; ny = 0.0f; nz = 0.0f; }

    // outputs: t_hit [0,N) | sphere_idx [N,2N) | hit_points [2N,5N) | normals [5N,8N)
    out[i]            = best_t;
    out[N_RAYS + i]   = any_hit ? (float)best_j : -1.0f;
    float* hp = out + 2 * N_RAYS;
    hp[3 * i + 0] = hx; hp[3 * i + 1] = hy; hp[3 * i + 2] = hz;
    float* hn = out + 5 * N_RAYS;
    hn[3 * i + 0] = nx; hn[3 * i + 1] = ny; hn[3 * i + 2] = nz;
}

extern "C" void kernel_launch(void* const* d_in, const int* in_sizes, int n_in,
                              void* d_out, int out_size, void* d_ws, size_t ws_size,
                              hipStream_t stream) {
    const float* ro = (const float*)d_in[0];
    const float* rd = (const float*)d_in[1];
    const float* sc = (const float*)d_in[2];
    const float* sr = (const float*)d_in[3];
    float* out = (float*)d_out;

    dim3 block(256);
    dim3 grid(N_RAYS / 256);
    ray_sphere_kernel<<<grid, block, 0, stream>>>(ro, rd, sc, sr, out);
}

// Round 3
// 85.973 us; speedup vs baseline: 1.6108x; 1.1697x over previous
//
#include <hip/hip_runtime.h>
#include <math.h>

#define N_RAYS 262144
#define N_SPHERES 256

__global__ __launch_bounds__(256) void ray_sphere_kernel(
    const float* __restrict__ ro,   // (N,3)
    const float* __restrict__ rd,   // (N,3)
    const float* __restrict__ sc,   // (M,3)
    const float* __restrict__ sr,   // (M,)
    float* __restrict__ out)        // 8N floats: t_hit | idx | hit_points | hit_normals
{
    __shared__ float4 sph[N_SPHERES];  // x,y,z = center, w = |c|^2 - r^2

    const int tid = threadIdx.x;
    {
        const float cx = sc[3 * tid + 0];
        const float cy = sc[3 * tid + 1];
        const float cz = sc[3 * tid + 2];
        const float r  = sr[tid];
        sph[tid] = make_float4(cx, cy, cz,
                               fmaf(cz, cz, fmaf(cy, cy, cx * cx)) - r * r);
    }
    __syncthreads();

    const int i = blockIdx.x * blockDim.x + tid;

    const float ox = ro[3 * i + 0], oy = ro[3 * i + 1], oz = ro[3 * i + 2];
    const float dx = rd[3 * i + 0], dy = rd[3 * i + 1], dz = rd[3 * i + 2];

    const float a       = fmaf(dz, dz, fmaf(dy, dy, dx * dx));
    const float d_dot_o = fmaf(dz, oz, fmaf(dy, oy, dx * ox));
    const float o_norm2 = fmaf(oz, oz, fmaf(oy, oy, ox * ox));
    const float inva    = 1.0f / a;
    const float nd      = -d_dot_o;     // fold into m's fma chain
    const float px = -2.0f * ox, py = -2.0f * oy, pz = -2.0f * oz;

    // Track the min in u-space: u = a*t = -hb -/+ sqrt(disc/4). a>0 so the
    // argmin and all sign tests are identical to t-space (monotone scaling);
    // one multiply by inva at the end recovers t.
    float best_u = INFINITY;
    int   best_j = 0;  // argmin of all-inf row is 0 (matches jnp.argmin)

    #pragma unroll 4
    for (int j = 0; j < N_SPHERES; ++j) {
        const float4 s = sph[j];
        const float m    = fmaf(dz, s.z, fmaf(dy, s.y, fmaf(dx, s.x, nd)));      // -b/2
        const float c    = fmaf(pz, s.z, fmaf(py, s.y, fmaf(px, s.x, o_norm2 + s.w)));
        const float disc = fmaf(m, m, -(a * c));                                  // disc/4
        // Wave-uniform skip: ~94% of (wave, sphere) pairs have no lane hitting.
        if (__ballot(disc >= 0.0f) != 0ull) {
            // Lanes with disc<0 get sq=NaN -> u=NaN -> all compares false ->
            // no update. No per-lane disc mask needed.
            const float sq = __builtin_amdgcn_sqrtf(disc);   // raw v_sqrt_f32
            const float u1 = m - sq;
            const float u2 = m + sq;
            const float u  = (u1 > 0.0f) ? u1 : u2;
            // valid <=> u > 0 (u2 >= u1, so t>0 iff selected root > 0)
            if (u > 0.0f && u < best_u) { best_u = u; best_j = j; }
        }
    }

    const float best_t = best_u * inva;
    const bool any_hit = isfinite(best_t);

    const float hx = fmaf(best_t, dx, ox);
    const float hy = fmaf(best_t, dy, oy);
    const float hz = fmaf(best_t, dz, oz);

    const float4 cs = sph[any_hit ? best_j : 0];
    float nx = hx - cs.x, ny = hy - cs.y, nz = hz - cs.z;
    const float inv_nrm = __builtin_amdgcn_rsqf(fmaf(nz, nz, fmaf(ny, ny, nx * nx)));
    nx *= inv_nrm; ny *= inv_nrm; nz *= inv_nrm;
    if (!any_hit) { nx = 0.0f; ny = 0.0f; nz = 0.0f; }

    // outputs: t_hit [0,N) | sphere_idx [N,2N) | hit_points [2N,5N) | normals [5N,8N)
    out[i]            = best_t;
    out[N_RAYS + i]   = any_hit ? (float)best_j : -1.0f;
    float* hp = out + 2 * N_RAYS;
    hp[3 * i + 0] = hx; hp[3 * i + 1] = hy; hp[3 * i + 2] = hz;
    float* hn = out + 5 * N_RAYS;
    hn[3 * i + 0] = nx; hn[3 * i + 1] = ny; hn[3 * i + 2] = nz;
}

extern "C" void kernel_launch(void* const* d_in, const int* in_sizes, int n_in,
                              void* d_out, int out_size, void* d_ws, size_t ws_size,
                              hipStream_t stream) {
    const float* ro = (const float*)d_in[0];
    const float* rd = (const float*)d_in[1];
    const float* sc = (const float*)d_in[2];
    const float* sr = (const float*)d_in[3];
    float* out = (float*)d_out;

    dim3 block(256);
    dim3 grid(N_RAYS / 256);
    ray_sphere_kernel<<<grid, block, 0, stream>>>(ro, rd, sc, sr, out);
}